// Round 1
// 230.263 us; speedup vs baseline: 1.2412x; 1.2412x over previous
//
#include <hip/hip_runtime.h>

// y[e] = W2 . relu(W1 . concat(z[src[e]], z[dst[e]]) + b1) + b2
// N=50000, D=128, H=512, E=500000. Compute-bound: 131 GFLOP in GEMM1.
// R8: all-H blocks. 512 threads = 8 waves, wave w owns h-slice w*64 of the
// full H=512 -> ONE gather per 64-edge tile (R7's hy grid split gathered
// every A-tile twice). acc stays [4][4] (64 regs) per wave. No atomicAdd:
// partials from the 8 waves combine via a 2KB LDS buffer, out written once
// (prep no longer zeroes out). launch_bounds(512,4): 68 VGPR + 34KB LDS ->
// 2 blocks/CU = 16 waves/CU (50% occ, was 37.5%).

typedef __bf16 bf16x8 __attribute__((ext_vector_type(8)));
typedef float f32x4 __attribute__((ext_vector_type(4)));

#define STRA 264   // 256 + 8 pad (ushort units)

__device__ __forceinline__ unsigned short f2b(float f) {
    unsigned int u = __float_as_uint(f);
    u = (u + 0x7fffu + ((u >> 16) & 1u)) >> 16;   // RNE
    return (unsigned short)u;
}

// zb: z as bf16 [N][128].  w1s: W1 swizzled to MFMA-B fragment order:
// w1s[(hblk*8 + kc)*512 + lane*8 + t] = bf16(W1[hblk*16 + (lane&15)][kc*32 + (lane>>4)*8 + t])
__global__ void prep_kernel(const float* __restrict__ z, const float* __restrict__ W1,
                            unsigned short* __restrict__ zb, unsigned short* __restrict__ w1s,
                            int nz4) {
    int stride = gridDim.x * blockDim.x;
    const int nw = 256 * 64;   // (hblk*8+kc) x lane
    const int total = nz4 + nw;
    for (int idx = blockIdx.x * blockDim.x + threadIdx.x; idx < total; idx += stride) {
        if (idx < nz4) {
            float4 v = ((const float4*)z)[idx];
            ushort4 o;
            o.x = f2b(v.x); o.y = f2b(v.y); o.z = f2b(v.z); o.w = f2b(v.w);
            ((ushort4*)zb)[idx] = o;
        } else {
            int u = idx - nz4;            // 0..16383
            int lane = u & 63;
            int blk  = u >> 6;            // hblk*8 + kc
            int h  = (blk >> 3) * 16 + (lane & 15);
            int kb = (blk & 7) * 32 + (lane >> 4) * 8;
            const float* src = W1 + h * 256 + kb;
            ushort4 o0, o1;
            float4 v0 = *(const float4*)(src);
            float4 v1 = *(const float4*)(src + 4);
            o0.x = f2b(v0.x); o0.y = f2b(v0.y); o0.z = f2b(v0.z); o0.w = f2b(v0.w);
            o1.x = f2b(v1.x); o1.y = f2b(v1.y); o1.z = f2b(v1.z); o1.w = f2b(v1.w);
            ushort4* dst = (ushort4*)(w1s + u * 8);
            dst[0] = o0; dst[1] = o1;
        }
    }
}

__global__ __launch_bounds__(512, 4)
void edge_mlp_kernel(const int* __restrict__ ei, const unsigned short* __restrict__ zb,
                     const unsigned short* __restrict__ w1s,
                     const float* __restrict__ b1, const float* __restrict__ W2,
                     const float* __restrict__ b2p, float* __restrict__ out, int E) {
    __shared__ unsigned short ldsA[64 * STRA];  // 33792 B : 64 edges x 256 k (bf16)
    __shared__ int ldsIdx[128];                 // 64 edges x {src,dst}

    const int tid  = threadIdx.x;
    const int lane = tid & 63;
    const int w    = tid >> 6;        // 0..7 : which 64-h slice of H=512
    const int l15  = lane & 15;
    const int l4   = lane >> 4;
    const int ebase = blockIdx.x * 64;

    // ---- broadcast edge indices: one coalesced load -> LDS ----
    if (tid < 128) {
        int e = ebase + (tid >> 1);
        int side = tid & 1;
        ldsIdx[tid] = (e < E) ? ei[side * E + e] : 0;
    }
    __syncthreads();

    // ---- gather A: 64 edges x (z[src] ++ z[dst]) as bf16 rows ----
    {
        const int g = tid >> 4;     // 32 groups of 16 lanes
        const int l = tid & 15;
        #pragma unroll
        for (int it = 0; it < 4; ++it) {
            int hr = it * 32 + g;          // half-row 0..127
            int m = hr >> 1, side = hr & 1;
            int row = ldsIdx[hr];
            uint4 v = *((const uint4*)(zb + (row << 7)) + l);
            *(uint4*)&ldsA[m * STRA + side * 128 + l * 8] = v;
        }
    }
    __syncthreads();

    f32x4 acc[4][4];
    #pragma unroll
    for (int i = 0; i < 4; i++)
        #pragma unroll
        for (int j = 0; j < 4; j++) acc[i][j] = (f32x4){0.f, 0.f, 0.f, 0.f};

    const unsigned aoff = l15 * STRA + l4 * 8;
    // hblk = w*4 + j;  B frag at w1s[(hblk*8 + kc)*512 + lane*8]
    const unsigned short* bp = w1s + ((w * 4) * 8) * 512 + lane * 8;

    #pragma unroll
    for (int kc = 0; kc < 8; ++kc) {
        uint4 b[4];
        #pragma unroll
        for (int j = 0; j < 4; j++)
            b[j] = *(const uint4*)(bp + (j * 8 + kc) * 512);
        bf16x8 a[4];
        #pragma unroll
        for (int i = 0; i < 4; i++)
            a[i] = *(const bf16x8*)&ldsA[aoff + i * 16 * STRA + kc * 32];
        #pragma unroll
        for (int i = 0; i < 4; i++)
            #pragma unroll
            for (int j = 0; j < 4; j++)
                acc[i][j] = __builtin_amdgcn_mfma_f32_16x16x32_bf16(
                    a[i], *(const bf16x8*)&b[j], acc[i][j], 0, 0, 0);
    }

    // fused epilogue: h = relu(acc + b1); y = sum_h h * W2[h]
    float y[4][4];
    #pragma unroll
    for (int i = 0; i < 4; i++)
        #pragma unroll
        for (int r = 0; r < 4; r++) y[i][r] = 0.f;

    #pragma unroll
    for (int j = 0; j < 4; j++) {
        int h = w * 64 + j * 16 + l15;
        float w2v = W2[h];
        float b1v = b1[h];
        #pragma unroll
        for (int i = 0; i < 4; i++)
            #pragma unroll
            for (int r = 0; r < 4; r++) {
                float hv = acc[i][j][r] + b1v;
                y[i][r] = fmaf(fmaxf(hv, 0.f), w2v, y[i][r]);
            }
    }

    // reduce over the 16 h-lanes (C layout: col = lane&15)
    #pragma unroll
    for (int i = 0; i < 4; i++)
        #pragma unroll
        for (int r = 0; r < 4; r++) {
            float v = y[i][r];
            v += __shfl_xor(v, 1);
            v += __shfl_xor(v, 2);
            v += __shfl_xor(v, 4);
            v += __shfl_xor(v, 8);
            y[i][r] = v;
        }

    __syncthreads();                 // all waves done reading ldsA
    float* ldsY = (float*)ldsA;      // reuse: [w][64 edges]  (2 KB)
    if (l15 == 0) {
        #pragma unroll
        for (int i = 0; i < 4; i++)
            #pragma unroll
            for (int r = 0; r < 4; r++) {
                int m = i * 16 + l4 * 4 + r;   // C layout: row=(lane>>4)*4+reg
                ldsY[w * 64 + m] = y[i][r];
            }
    }
    __syncthreads();
    if (tid < 64) {
        int e = ebase + tid;
        if (e < E) {
            float v = b2p[0];
            #pragma unroll
            for (int k = 0; k < 8; ++k) v += ldsY[k * 64 + tid];
            out[e] = v;              // single writer per e -> plain store
        }
    }
}

extern "C" void kernel_launch(void* const* d_in, const int* in_sizes, int n_in,
                              void* d_out, int out_size, void* d_ws, size_t ws_size,
                              hipStream_t stream) {
    const float* z  = (const float*)d_in[0];
    const int*   ei = (const int*)d_in[1];
    const float* W1 = (const float*)d_in[2];
    const float* b1 = (const float*)d_in[3];
    const float* W2 = (const float*)d_in[4];
    const float* b2 = (const float*)d_in[5];
    float* out = (float*)d_out;

    const int E  = in_sizes[1] / 2;   // 500000
    const int NZ = in_sizes[0];       // 6400000 = N*D

    unsigned short* zb  = (unsigned short*)d_ws;       // 12.8 MB
    unsigned short* w1s = zb + NZ;                     // 256 KB (swizzled W1)

    prep_kernel<<<2048, 256, 0, stream>>>(z, W1, zb, w1s, NZ / 4);

    const int eblocks = (E + 63) / 64;                 // 7813
    edge_mlp_kernel<<<eblocks, 512, 0, stream>>>(ei, zb, w1s, b1, W2, b2, out, E);
}